// Round 6
// baseline (391.433 us; speedup 1.0000x reference)
//
#include <hip/hip_runtime.h>

#define EMBED 4096
#define NTOK 8192
#define LN_EPS 1e-5f

#define NB_CONVW2 (EMBED * EMBED / (256 * 8))   // 8192
#define NB_CONVW1 (EMBED * 64 / (256 * 8))      // 128

typedef float f4_t __attribute__((ext_vector_type(4)));
typedef __bf16 bf16x8 __attribute__((ext_vector_type(8)));
typedef unsigned short us8_t __attribute__((ext_vector_type(8)));

__device__ __forceinline__ unsigned short f2bf(float f) {
    unsigned int u = __float_as_uint(f);
    u += 0x7fffu + ((u >> 16) & 1u);   // RNE; inputs are finite
    return (unsigned short)(u >> 16);
}

typedef const __attribute__((address_space(1))) unsigned int gas_t;
typedef __attribute__((address_space(3))) unsigned int las_t;

__device__ __forceinline__ void gl_lds16(const void* g, void* l) {
    __builtin_amdgcn_global_load_lds((gas_t*)g, (las_t*)l, 16, 0, 0);
}

__device__ __forceinline__ void conv_body(const float* __restrict__ src,
                                          unsigned short* __restrict__ dst,
                                          int i) {
    const f4_t* in4 = (const f4_t*)src;
    f4_t v0 = in4[(size_t)i * 2];
    f4_t v1 = in4[(size_t)i * 2 + 1];
    us8_t o;
    o[0] = f2bf(v0.x); o[1] = f2bf(v0.y); o[2] = f2bf(v0.z); o[3] = f2bf(v0.w);
    o[4] = f2bf(v1.x); o[5] = f2bf(v1.y); o[6] = f2bf(v1.z); o[7] = f2bf(v1.w);
    *(us8_t*)(dst + (size_t)i * 8) = o;
}

// ---------------- fused prep: compact | prepG | conv w2 | conv w1 | enc01 ---
__global__ __launch_bounds__(256) void k_prep(
    const float* __restrict__ prompts, const int* __restrict__ types,
    const float* __restrict__ pw, const float* __restrict__ pb,
    const float* __restrict__ bw, const float* __restrict__ bb,
    const float* __restrict__ temb,
    const float* __restrict__ w1, const float* __restrict__ b1,
    const float* __restrict__ w2,
    int* __restrict__ idx, int* __restrict__ counters,
    float* __restrict__ G, float* __restrict__ cbar,
    unsigned short* __restrict__ w1b, unsigned short* __restrict__ w2b,
    float* __restrict__ out)
{
    int bid = blockIdx.x;
    int t = threadIdx.x;

    if (bid == 0) {
        // ---- compact type-2 token indices ----
        __shared__ int cnt;
        if (t == 0) cnt = 0;
        __syncthreads();
        for (int i = t; i < NTOK; i += 256) {
            if (types[i] == 2) {
                int s = atomicAdd(&cnt, 1);
                idx[s] = i;
            }
        }
        __syncthreads();
        if (t == 0) {
            counters[0] = cnt;
            counters[1] = (cnt + 127) & ~127;
        }
        return;
    }

    if (bid <= 66) {
        // ---- LN moment matrices: row i of G (i<65) or cbar (i==65) ----
        int i = bid - 1;
        __shared__ float sA[64][66];
        int wave = t >> 6, lane = t & 63;
        float part[17];
#pragma unroll
        for (int jj = 0; jj < 17; ++jj) part[jj] = 0.f;
        for (int e0 = 0; e0 < EMBED; e0 += 64) {
            __syncthreads();
#pragma unroll
            for (int q = 0; q < 4; ++q) {
                int v = t + 256 * q;          // 0..1023
                int r = v >> 4, c4 = v & 15;  // row 0..63, f4-col 0..15
                f4_t val = *(const f4_t*)(w1 + (size_t)(e0 + r) * 64 + c4 * 4);
                sA[r][c4 * 4 + 0] = val.x;
                sA[r][c4 * 4 + 1] = val.y;
                sA[r][c4 * 4 + 2] = val.z;
                sA[r][c4 * 4 + 3] = val.w;
            }
            if (t < 64) sA[t][64] = b1[e0 + t];
            __syncthreads();
            float ai = (i < 65) ? sA[lane][i] : 1.f;   // i==65 -> cbar row
#pragma unroll
            for (int jj = 0; jj < 16; ++jj)
                part[jj] += ai * sA[lane][wave * 16 + jj];
            if (wave == 3) part[16] += ai * sA[lane][64];
        }
#pragma unroll
        for (int jj = 0; jj < 17; ++jj) {
            float v = part[jj];
            v += __shfl_down(v, 32);
            v += __shfl_down(v, 16);
            v += __shfl_down(v, 8);
            v += __shfl_down(v, 4);
            v += __shfl_down(v, 2);
            v += __shfl_down(v, 1);
            part[jj] = v;
        }
        if (lane == 0) {
            int nj = (wave == 3) ? 17 : 16;
            for (int jj = 0; jj < nj; ++jj) {
                int j = (jj == 16) ? 64 : (wave * 16 + jj);
                float s = part[jj] * (1.f / 4096.f);
                if (i < 65) G[i * 65 + j] = s;
                else        cbar[j] = s;
            }
        }
        return;
    }

    if (bid < 67 + NB_CONVW2) {
        conv_body(w2, w2b, (bid - 67) * 256 + t);
        return;
    }

    if (bid < 67 + NB_CONVW2 + NB_CONVW1) {
        conv_body(w1, w1b, (bid - 67 - NB_CONVW2) * 256 + t);
        return;
    }

    // ---- enc01: type 0/1 rows ----
    {
        int token = bid - (67 + NB_CONVW2 + NB_CONVW1);
        int ty = types[token];
        if (ty >= 2) return;
        const float* x = prompts + (size_t)token * 64;
        float x0 = x[0], x1 = x[1], x2 = x[2], x3 = x[3];
        f4_t* o4 = (f4_t*)(out + (size_t)token * EMBED);
        if (ty == 0) {
            const f4_t* w4 = (const f4_t*)pw;
            const f4_t* b4 = (const f4_t*)pb;
            const f4_t* te4 = (const f4_t*)temb;
#pragma unroll
            for (int j = 0; j < 4; ++j) {
                int e4 = t + 256 * j;
                f4_t wa = w4[e4 * 2], wb = w4[e4 * 2 + 1];
                f4_t bv = b4[e4], tv = te4[e4];
                f4_t r;
                r.x = x0 * wa.x + x1 * wa.y + bv.x + tv.x;
                r.y = x0 * wa.z + x1 * wa.w + bv.y + tv.y;
                r.z = x0 * wb.x + x1 * wb.y + bv.z + tv.z;
                r.w = x0 * wb.z + x1 * wb.w + bv.w + tv.w;
                o4[e4] = r;
            }
        } else {
            const f4_t* w4 = (const f4_t*)bw;
            const f4_t* b4 = (const f4_t*)bb;
            const f4_t* te4 = (const f4_t*)(temb + EMBED);
#pragma unroll
            for (int j = 0; j < 4; ++j) {
                int e4 = t + 256 * j;
                f4_t w0 = w4[e4 * 4 + 0], w1v = w4[e4 * 4 + 1];
                f4_t w2v = w4[e4 * 4 + 2], w3v = w4[e4 * 4 + 3];
                f4_t bv = b4[e4], tv = te4[e4];
                f4_t r;
                r.x = x0 * w0.x + x1 * w0.y + x2 * w0.z + x3 * w0.w + bv.x + tv.x;
                r.y = x0 * w1v.x + x1 * w1v.y + x2 * w1v.z + x3 * w1v.w + bv.y + tv.y;
                r.z = x0 * w2v.x + x1 * w2v.y + x2 * w2v.z + x3 * w2v.w + bv.z + tv.z;
                r.w = x0 * w3v.x + x1 * w3v.y + x2 * w3v.z + x3 * w3v.w + bv.w + tv.w;
                o4[e4] = r;
            }
        }
    }
}

// ---------------- kernel 4: LN stats per type-2 row + bf16 x gather ------
__global__ __launch_bounds__(256) void k_stats(const float* __restrict__ prompts,
                                               const int* __restrict__ idx,
                                               const int* __restrict__ counters,
                                               const float* __restrict__ cbar,
                                               const float* __restrict__ G,
                                               float* __restrict__ mu,
                                               float* __restrict__ rstd,
                                               unsigned short* __restrict__ xbuf) {
    int count = counters[0], padded = counters[1];
    int base = blockIdx.x * 4;
    if (base >= padded) return;
    __shared__ float sG[65 * 65];
    __shared__ __align__(16) float xs[4][66];
    int t = threadIdx.x;
    for (int v = t; v < 65 * 65; v += 256) sG[v] = G[v];
    int r = t >> 6, lane = t & 63;
    int m = base + r;
    bool vld = (m < count);
    float xv = vld ? prompts[(size_t)idx[m] * 64 + lane] : 0.f;
    xs[r][lane] = xv;
    if (lane == 0) xs[r][64] = vld ? 1.f : 0.f;
    xbuf[(size_t)m * 64 + lane] = vld ? f2bf(xv) : (unsigned short)0;
    __syncthreads();
    float mu_p, m2_p;
    {
        float xi = xs[r][lane];
        mu_p = cbar[lane] * xi;
        const float* Gr = sG + lane * 65;
        float rd = 0.f;
        for (int j = 0; j < 65; ++j) rd += Gr[j] * xs[r][j];
        m2_p = xi * rd;
    }
    if (lane == 0) {   // i = 64 term
        float xi = xs[r][64];
        mu_p += cbar[64] * xi;
        const float* Gr = sG + 64 * 65;
        float rd = 0.f;
        for (int j = 0; j < 65; ++j) rd += Gr[j] * xs[r][j];
        m2_p += xi * rd;
    }
    for (int off = 32; off > 0; off >>= 1) {
        mu_p += __shfl_down(mu_p, off);
        m2_p += __shfl_down(m2_p, off);
    }
    if (lane == 0) {
        if (vld) {
            mu[m] = mu_p;
            rstd[m] = rsqrtf(fmaxf(m2_p - mu_p * mu_p, 0.f) + LN_EPS);
        } else {
            mu[m] = 0.f;
            rstd[m] = 0.f;
        }
    }
}

// ---------------- kernel 5: lin1 as MFMA GEMM, fused LN+ReLU -> hbuf -----
// BK=64 single pass: both 32-col halves staged, ONE barrier pair total.
__global__ __launch_bounds__(256) void k_lin1m(const unsigned short* __restrict__ xbuf,
                                               const unsigned short* __restrict__ w1b,
                                               const int* __restrict__ counters,
                                               const float* __restrict__ b1,
                                               const float* __restrict__ gamma,
                                               const float* __restrict__ beta,
                                               const float* __restrict__ mu,
                                               const float* __restrict__ rstd,
                                               unsigned short* __restrict__ hbuf) {
    int padded = counters[1];
    int m0 = blockIdx.y * 128;
    if (m0 >= padded) return;
    int n0 = blockIdx.x * 128;

    __shared__ unsigned short At[2][128 * 32];
    __shared__ unsigned short Bt[2][128 * 32];

    int t = threadIdx.x;
    int lane = t & 63, wave = t >> 6;
    int wm = (wave >> 1) * 64;
    int wn = (wave & 1) * 64;

    int srow = t >> 2, skg = t & 3;
    const unsigned short* Ag = xbuf + (size_t)(m0 + srow) * 64 + skg * 8;
    const unsigned short* Bg = w1b + (size_t)(n0 + srow) * 64 + skg * 8;
    char* A0 = (char*)At[0]; char* A1 = (char*)At[1];
    char* B0 = (char*)Bt[0]; char* B1 = (char*)Bt[1];
    int ldsw = (t & ~63) * 16;

    f4_t acc[4][4];
#pragma unroll
    for (int i = 0; i < 4; ++i)
#pragma unroll
        for (int j = 0; j < 4; ++j) acc[i][j] = (f4_t)0.f;

    int fr = lane & 15;
    int quad = lane >> 4;

    gl_lds16(Ag,                A0 + ldsw);
    gl_lds16(Ag + 64 * 64,      A0 + 4096 + ldsw);
    gl_lds16(Ag + 32,           A1 + ldsw);
    gl_lds16(Ag + 64 * 64 + 32, A1 + 4096 + ldsw);
    gl_lds16(Bg,                B0 + ldsw);
    gl_lds16(Bg + 64 * 64,      B0 + 4096 + ldsw);
    gl_lds16(Bg + 32,           B1 + ldsw);
    gl_lds16(Bg + 64 * 64 + 32, B1 + 4096 + ldsw);
    __syncthreads();

    {
        bf16x8 a[4], b[4];
#pragma unroll
        for (int i = 0; i < 4; ++i) {
            a[i] = *(const bf16x8*)(A0 + (wm + i * 16 + fr) * 64 + quad * 16);
            b[i] = *(const bf16x8*)(B0 + (wn + i * 16 + fr) * 64 + quad * 16);
        }
#pragma unroll
        for (int i = 0; i < 4; ++i)
#pragma unroll
            for (int j = 0; j < 4; ++j)
                acc[i][j] = __builtin_amdgcn_mfma_f32_16x16x32_bf16(a[i], b[j], acc[i][j], 0, 0, 0);
#pragma unroll
        for (int i = 0; i < 4; ++i) {
            a[i] = *(const bf16x8*)(A1 + (wm + i * 16 + fr) * 64 + quad * 16);
            b[i] = *(const bf16x8*)(B1 + (wn + i * 16 + fr) * 64 + quad * 16);
        }
#pragma unroll
        for (int i = 0; i < 4; ++i)
#pragma unroll
            for (int j = 0; j < 4; ++j)
                acc[i][j] = __builtin_amdgcn_mfma_f32_16x16x32_bf16(a[i], b[j], acc[i][j], 0, 0, 0);
    }

#pragma unroll
    for (int i = 0; i < 4; ++i) {
#pragma unroll
        for (int r = 0; r < 4; ++r) {
            int grow = m0 + wm + i * 16 + quad * 4 + r;   // always < padded
            float muv = mu[grow], rsv = rstd[grow];
            unsigned short* hrow = hbuf + (size_t)grow * EMBED;
#pragma unroll
            for (int j = 0; j < 4; ++j) {
                int gcol = n0 + wn + j * 16 + fr;
                float h = (acc[i][j][r] + b1[gcol] - muv) * rsv * gamma[gcol] + beta[gcol];
                hrow[gcol] = f2bf(fmaxf(h, 0.f));
            }
        }
    }
}

// ---------------- kernel 6: C[m][n] = h[m].w2[n] + b2[n] + te2[n] --------
// R2 128x128/BK=32 proven body + T1 XCD-chunked bijective swizzle over the
// ACTIVE block range (active is always a multiple of 8): each XCD gets a
// contiguous run of nids; consecutive nids share the m-row A-panel -> A
// stays hot in that XCD's L2 instead of being fetched by all 8 XCDs.
__global__ __launch_bounds__(256) void k_gemm(const unsigned short* __restrict__ hbuf,
                                              const unsigned short* __restrict__ w2b,
                                              const int* __restrict__ idx,
                                              const int* __restrict__ counters,
                                              const float* __restrict__ b2,
                                              const float* __restrict__ te2,
                                              float* __restrict__ out) {
    int count = counters[0], padded = counters[1];
    int flat = blockIdx.y * 32 + blockIdx.x;
    int active = (padded >> 7) * 32;          // multiple of 32 (and of 8)
    if (flat >= active) return;
    int q = active >> 3;
    int nid = (flat & 7) * q + (flat >> 3);   // bijective XCD-chunked swizzle
    int m0 = (nid >> 5) * 128;                // n varies fastest within chunk
    int n0 = (nid & 31) * 128;

    __shared__ unsigned short At[128 * 32];
    __shared__ unsigned short Bt[128 * 32];

    int t = threadIdx.x;
    int lane = t & 63, wave = t >> 6;
    int wm = (wave >> 1) * 64;
    int wn = (wave & 1) * 64;

    int srow = t >> 2, skg = t & 3;
    const unsigned short* Ag = hbuf + (size_t)(m0 + srow) * EMBED + skg * 8;
    const unsigned short* Bg = w2b + (size_t)(n0 + srow) * EMBED + skg * 8;
    char* AtC = (char*)At;
    char* BtC = (char*)Bt;
    int ldsw = (t & ~63) * 16;

    f4_t acc[4][4];
#pragma unroll
    for (int i = 0; i < 4; ++i)
#pragma unroll
        for (int j = 0; j < 4; ++j) acc[i][j] = (f4_t)0.f;

    int fr = lane & 15;
    int quad = lane >> 4;

    for (int k0 = 0; k0 < EMBED; k0 += 32) {
        __syncthreads();
        gl_lds16(Ag + k0,               AtC + ldsw);
        gl_lds16(Ag + 64 * EMBED + k0,  AtC + 4096 + ldsw);
        gl_lds16(Bg + k0,               BtC + ldsw);
        gl_lds16(Bg + 64 * EMBED + k0,  BtC + 4096 + ldsw);
        __syncthreads();

        bf16x8 a[4], b[4];
#pragma unroll
        for (int i = 0; i < 4; ++i) {
            a[i] = *(const bf16x8*)(AtC + (wm + i * 16 + fr) * 64 + quad * 16);
            b[i] = *(const bf16x8*)(BtC + (wn + i * 16 + fr) * 64 + quad * 16);
        }
#pragma unroll
        for (int i = 0; i < 4; ++i)
#pragma unroll
            for (int j = 0; j < 4; ++j)
                acc[i][j] = __builtin_amdgcn_mfma_f32_16x16x32_bf16(a[i], b[j], acc[i][j], 0, 0, 0);
    }

#pragma unroll
    for (int i = 0; i < 4; ++i) {
#pragma unroll
        for (int r = 0; r < 4; ++r) {
            int grow = m0 + wm + i * 16 + quad * 4 + r;
            if (grow < count) {
                float* orow = out + (size_t)idx[grow] * EMBED;
#pragma unroll
                for (int j = 0; j < 4; ++j) {
                    int gcol = n0 + wn + j * 16 + fr;
                    orow[gcol] = acc[i][j][r] + b2[gcol] + te2[gcol];
                }
            }
        }
    }
}

extern "C" void kernel_launch(void* const* d_in, const int* in_sizes, int n_in,
                              void* d_out, int out_size, void* d_ws, size_t ws_size,
                              hipStream_t stream) {
    const float* prompts  = (const float*)d_in[0];
    const int*   types    = (const int*)d_in[1];
    const float* point_w  = (const float*)d_in[2];
    const float* point_b  = (const float*)d_in[3];
    const float* box_w    = (const float*)d_in[4];
    const float* box_b    = (const float*)d_in[5];
    const float* poly_w1  = (const float*)d_in[6];
    const float* poly_b1  = (const float*)d_in[7];
    const float* ln_g     = (const float*)d_in[8];
    const float* ln_b     = (const float*)d_in[9];
    const float* poly_w2  = (const float*)d_in[10];
    const float* poly_b2  = (const float*)d_in[11];
    const float* type_emb = (const float*)d_in[12];
    float* out = (float*)d_out;

    char* ws = (char*)d_ws;
    int*   counters = (int*)ws;                               // 2 ints
    int*   idx      = (int*)(ws + 256);                       // 8192 ints
    float* cbar     = (float*)(ws + 33280);                   // 65 f
    float* G        = (float*)(ws + 33792);                   // 65*65 f
    float* muarr    = (float*)(ws + 51200);                   // 8192 f
    float* rstdarr  = (float*)(ws + 84224);                   // 8192 f
    unsigned short* xbuf = (unsigned short*)(ws + 131072);    // 1 MB
    unsigned short* w1b  = (unsigned short*)(ws + 131072 + 1048576);  // 512 KB
    unsigned short* w2b  = (unsigned short*)(ws + 2097152);   // 32 MB
    unsigned short* hbuf = (unsigned short*)(ws + 2097152 + (size_t)EMBED * EMBED * 2); // 64 MB

    int nprep = 67 + NB_CONVW2 + NB_CONVW1 + NTOK;
    k_prep<<<nprep, 256, 0, stream>>>(prompts, types, point_w, point_b,
                                      box_w, box_b, type_emb,
                                      poly_w1, poly_b1, poly_w2,
                                      idx, counters, G, cbar, w1b, w2b, out);
    k_stats<<<NTOK / 4, 256, 0, stream>>>(prompts, idx, counters, cbar, G,
                                          muarr, rstdarr, xbuf);
    k_lin1m<<<dim3(EMBED / 128, NTOK / 128), 256, 0, stream>>>(
        xbuf, w1b, counters, poly_b1, ln_g, ln_b, muarr, rstdarr, hbuf);
    k_gemm<<<dim3(EMBED / 128, NTOK / 128), 256, 0, stream>>>(
        hbuf, w2b, idx, counters, poly_b2, type_emb + 2 * EMBED, out);
}

// Round 7
// 380.563 us; speedup vs baseline: 1.0286x; 1.0286x over previous
//
#include <hip/hip_runtime.h>

#define EMBED 4096
#define NTOK 8192
#define LN_EPS 1e-5f

#define NB_CONVW2 (EMBED * EMBED / (256 * 8))   // 8192
#define NB_CONVW1 (EMBED * 64 / (256 * 8))      // 128

typedef float f4_t __attribute__((ext_vector_type(4)));
typedef __bf16 bf16x8 __attribute__((ext_vector_type(8)));
typedef unsigned short us8_t __attribute__((ext_vector_type(8)));

__device__ __forceinline__ unsigned short f2bf(float f) {
    unsigned int u = __float_as_uint(f);
    u += 0x7fffu + ((u >> 16) & 1u);   // RNE; inputs are finite
    return (unsigned short)(u >> 16);
}

typedef const __attribute__((address_space(1))) unsigned int gas_t;
typedef __attribute__((address_space(3))) unsigned int las_t;

__device__ __forceinline__ void gl_lds16(const void* g, void* l) {
    __builtin_amdgcn_global_load_lds((gas_t*)g, (las_t*)l, 16, 0, 0);
}

__device__ __forceinline__ void conv_body(const float* __restrict__ src,
                                          unsigned short* __restrict__ dst,
                                          int i) {
    const f4_t* in4 = (const f4_t*)src;
    f4_t v0 = in4[(size_t)i * 2];
    f4_t v1 = in4[(size_t)i * 2 + 1];
    us8_t o;
    o[0] = f2bf(v0.x); o[1] = f2bf(v0.y); o[2] = f2bf(v0.z); o[3] = f2bf(v0.w);
    o[4] = f2bf(v1.x); o[5] = f2bf(v1.y); o[6] = f2bf(v1.z); o[7] = f2bf(v1.w);
    *(us8_t*)(dst + (size_t)i * 8) = o;
}

// ---------------- fused prep: compact | prepG | conv w2 | conv w1 | enc01 ---
__global__ __launch_bounds__(256) void k_prep(
    const float* __restrict__ prompts, const int* __restrict__ types,
    const float* __restrict__ pw, const float* __restrict__ pb,
    const float* __restrict__ bw, const float* __restrict__ bb,
    const float* __restrict__ temb,
    const float* __restrict__ w1, const float* __restrict__ b1,
    const float* __restrict__ w2,
    int* __restrict__ idx, int* __restrict__ counters,
    float* __restrict__ G, float* __restrict__ cbar,
    unsigned short* __restrict__ w1b, unsigned short* __restrict__ w2b,
    float* __restrict__ out)
{
    int bid = blockIdx.x;
    int t = threadIdx.x;

    if (bid == 0) {
        // ---- compact type-2 token indices ----
        __shared__ int cnt;
        if (t == 0) cnt = 0;
        __syncthreads();
        for (int i = t; i < NTOK; i += 256) {
            if (types[i] == 2) {
                int s = atomicAdd(&cnt, 1);
                idx[s] = i;
            }
        }
        __syncthreads();
        if (t == 0) {
            counters[0] = cnt;
            counters[1] = (cnt + 127) & ~127;
        }
        return;
    }

    if (bid <= 66) {
        // ---- LN moment matrices: row i of G (i<65) or cbar (i==65) ----
        int i = bid - 1;
        __shared__ float sA[64][66];
        int wave = t >> 6, lane = t & 63;
        float part[17];
#pragma unroll
        for (int jj = 0; jj < 17; ++jj) part[jj] = 0.f;
        for (int e0 = 0; e0 < EMBED; e0 += 64) {
            __syncthreads();
#pragma unroll
            for (int q = 0; q < 4; ++q) {
                int v = t + 256 * q;          // 0..1023
                int r = v >> 4, c4 = v & 15;  // row 0..63, f4-col 0..15
                f4_t val = *(const f4_t*)(w1 + (size_t)(e0 + r) * 64 + c4 * 4);
                sA[r][c4 * 4 + 0] = val.x;
                sA[r][c4 * 4 + 1] = val.y;
                sA[r][c4 * 4 + 2] = val.z;
                sA[r][c4 * 4 + 3] = val.w;
            }
            if (t < 64) sA[t][64] = b1[e0 + t];
            __syncthreads();
            float ai = (i < 65) ? sA[lane][i] : 1.f;   // i==65 -> cbar row
#pragma unroll
            for (int jj = 0; jj < 16; ++jj)
                part[jj] += ai * sA[lane][wave * 16 + jj];
            if (wave == 3) part[16] += ai * sA[lane][64];
        }
#pragma unroll
        for (int jj = 0; jj < 17; ++jj) {
            float v = part[jj];
            v += __shfl_down(v, 32);
            v += __shfl_down(v, 16);
            v += __shfl_down(v, 8);
            v += __shfl_down(v, 4);
            v += __shfl_down(v, 2);
            v += __shfl_down(v, 1);
            part[jj] = v;
        }
        if (lane == 0) {
            int nj = (wave == 3) ? 17 : 16;
            for (int jj = 0; jj < nj; ++jj) {
                int j = (jj == 16) ? 64 : (wave * 16 + jj);
                float s = part[jj] * (1.f / 4096.f);
                if (i < 65) G[i * 65 + j] = s;
                else        cbar[j] = s;
            }
        }
        return;
    }

    if (bid < 67 + NB_CONVW2) {
        conv_body(w2, w2b, (bid - 67) * 256 + t);
        return;
    }

    if (bid < 67 + NB_CONVW2 + NB_CONVW1) {
        conv_body(w1, w1b, (bid - 67 - NB_CONVW2) * 256 + t);
        return;
    }

    // ---- enc01: type 0/1 rows ----
    {
        int token = bid - (67 + NB_CONVW2 + NB_CONVW1);
        int ty = types[token];
        if (ty >= 2) return;
        const float* x = prompts + (size_t)token * 64;
        float x0 = x[0], x1 = x[1], x2 = x[2], x3 = x[3];
        f4_t* o4 = (f4_t*)(out + (size_t)token * EMBED);
        if (ty == 0) {
            const f4_t* w4 = (const f4_t*)pw;
            const f4_t* b4 = (const f4_t*)pb;
            const f4_t* te4 = (const f4_t*)temb;
#pragma unroll
            for (int j = 0; j < 4; ++j) {
                int e4 = t + 256 * j;
                f4_t wa = w4[e4 * 2], wb = w4[e4 * 2 + 1];
                f4_t bv = b4[e4], tv = te4[e4];
                f4_t r;
                r.x = x0 * wa.x + x1 * wa.y + bv.x + tv.x;
                r.y = x0 * wa.z + x1 * wa.w + bv.y + tv.y;
                r.z = x0 * wb.x + x1 * wb.y + bv.z + tv.z;
                r.w = x0 * wb.z + x1 * wb.w + bv.w + tv.w;
                o4[e4] = r;
            }
        } else {
            const f4_t* w4 = (const f4_t*)bw;
            const f4_t* b4 = (const f4_t*)bb;
            const f4_t* te4 = (const f4_t*)(temb + EMBED);
#pragma unroll
            for (int j = 0; j < 4; ++j) {
                int e4 = t + 256 * j;
                f4_t w0 = w4[e4 * 4 + 0], w1v = w4[e4 * 4 + 1];
                f4_t w2v = w4[e4 * 4 + 2], w3v = w4[e4 * 4 + 3];
                f4_t bv = b4[e4], tv = te4[e4];
                f4_t r;
                r.x = x0 * w0.x + x1 * w0.y + x2 * w0.z + x3 * w0.w + bv.x + tv.x;
                r.y = x0 * w1v.x + x1 * w1v.y + x2 * w1v.z + x3 * w1v.w + bv.y + tv.y;
                r.z = x0 * w2v.x + x1 * w2v.y + x2 * w2v.z + x3 * w2v.w + bv.z + tv.z;
                r.w = x0 * w3v.x + x1 * w3v.y + x2 * w3v.z + x3 * w3v.w + bv.w + tv.w;
                o4[e4] = r;
            }
        }
    }
}

// ---------------- kernel 4: LN stats per type-2 row + bf16 x gather ------
__global__ __launch_bounds__(256) void k_stats(const float* __restrict__ prompts,
                                               const int* __restrict__ idx,
                                               const int* __restrict__ counters,
                                               const float* __restrict__ cbar,
                                               const float* __restrict__ G,
                                               float* __restrict__ mu,
                                               float* __restrict__ rstd,
                                               unsigned short* __restrict__ xbuf) {
    int count = counters[0], padded = counters[1];
    int base = blockIdx.x * 4;
    if (base >= padded) return;
    __shared__ float sG[65 * 65];
    __shared__ __align__(16) float xs[4][66];
    int t = threadIdx.x;
    for (int v = t; v < 65 * 65; v += 256) sG[v] = G[v];
    int r = t >> 6, lane = t & 63;
    int m = base + r;
    bool vld = (m < count);
    float xv = vld ? prompts[(size_t)idx[m] * 64 + lane] : 0.f;
    xs[r][lane] = xv;
    if (lane == 0) xs[r][64] = vld ? 1.f : 0.f;
    xbuf[(size_t)m * 64 + lane] = vld ? f2bf(xv) : (unsigned short)0;
    __syncthreads();
    float mu_p, m2_p;
    {
        float xi = xs[r][lane];
        mu_p = cbar[lane] * xi;
        const float* Gr = sG + lane * 65;
        float rd = 0.f;
        for (int j = 0; j < 65; ++j) rd += Gr[j] * xs[r][j];
        m2_p = xi * rd;
    }
    if (lane == 0) {   // i = 64 term
        float xi = xs[r][64];
        mu_p += cbar[64] * xi;
        const float* Gr = sG + 64 * 65;
        float rd = 0.f;
        for (int j = 0; j < 65; ++j) rd += Gr[j] * xs[r][j];
        m2_p += xi * rd;
    }
    for (int off = 32; off > 0; off >>= 1) {
        mu_p += __shfl_down(mu_p, off);
        m2_p += __shfl_down(m2_p, off);
    }
    if (lane == 0) {
        if (vld) {
            mu[m] = mu_p;
            rstd[m] = rsqrtf(fmaxf(m2_p - mu_p * mu_p, 0.f) + LN_EPS);
        } else {
            mu[m] = 0.f;
            rstd[m] = 0.f;
        }
    }
}

// ---------------- kernel 5: lin1 as MFMA GEMM, fused LN+ReLU -> hbuf -----
// R2 proven body: BK=32, 16 KB LDS.
__global__ __launch_bounds__(256) void k_lin1m(const unsigned short* __restrict__ xbuf,
                                               const unsigned short* __restrict__ w1b,
                                               const int* __restrict__ counters,
                                               const float* __restrict__ b1,
                                               const float* __restrict__ gamma,
                                               const float* __restrict__ beta,
                                               const float* __restrict__ mu,
                                               const float* __restrict__ rstd,
                                               unsigned short* __restrict__ hbuf) {
    int padded = counters[1];
    int m0 = blockIdx.y * 128;
    if (m0 >= padded) return;
    int n0 = blockIdx.x * 128;

    __shared__ unsigned short At[128 * 32];
    __shared__ unsigned short Bt[128 * 32];

    int t = threadIdx.x;
    int lane = t & 63, wave = t >> 6;
    int wm = (wave >> 1) * 64;
    int wn = (wave & 1) * 64;

    int srow = t >> 2, skg = t & 3;
    const unsigned short* Ag = xbuf + (size_t)(m0 + srow) * 64 + skg * 8;
    const unsigned short* Bg = w1b + (size_t)(n0 + srow) * 64 + skg * 8;
    char* AtC = (char*)At;
    char* BtC = (char*)Bt;
    int ldsw = (t & ~63) * 16;

    f4_t acc[4][4];
#pragma unroll
    for (int i = 0; i < 4; ++i)
#pragma unroll
        for (int j = 0; j < 4; ++j) acc[i][j] = (f4_t)0.f;

    int fr = lane & 15;
    int quad = lane >> 4;

#pragma unroll
    for (int k0 = 0; k0 < 64; k0 += 32) {
        __syncthreads();
        gl_lds16(Ag + k0,            AtC + ldsw);
        gl_lds16(Ag + 64 * 64 + k0,  AtC + 4096 + ldsw);
        gl_lds16(Bg + k0,            BtC + ldsw);
        gl_lds16(Bg + 64 * 64 + k0,  BtC + 4096 + ldsw);
        __syncthreads();

        bf16x8 a[4], b[4];
#pragma unroll
        for (int i = 0; i < 4; ++i) {
            a[i] = *(const bf16x8*)(AtC + (wm + i * 16 + fr) * 64 + quad * 16);
            b[i] = *(const bf16x8*)(BtC + (wn + i * 16 + fr) * 64 + quad * 16);
        }
#pragma unroll
        for (int i = 0; i < 4; ++i)
#pragma unroll
            for (int j = 0; j < 4; ++j)
                acc[i][j] = __builtin_amdgcn_mfma_f32_16x16x32_bf16(a[i], b[j], acc[i][j], 0, 0, 0);
    }

#pragma unroll
    for (int i = 0; i < 4; ++i) {
#pragma unroll
        for (int r = 0; r < 4; ++r) {
            int grow = m0 + wm + i * 16 + quad * 4 + r;   // always < padded
            float muv = mu[grow], rsv = rstd[grow];
            unsigned short* hrow = hbuf + (size_t)grow * EMBED;
#pragma unroll
            for (int j = 0; j < 4; ++j) {
                int gcol = n0 + wn + j * 16 + fr;
                float h = (acc[i][j][r] + b1[gcol] - muv) * rsv * gamma[gcol] + beta[gcol];
                hrow[gcol] = f2bf(fmaxf(h, 0.f));
            }
        }
    }
}

// ---------------- kernel 6: C[m][n] = h[m].w2[n] + b2[n] + te2[n] --------
// R2 128x128/BK=32 proven body + T1 XCD-chunked bijective swizzle (R6:
// isolated -2.4 us, MfmaUtil 33.3->34.7; FETCH +39 MB but HBM has 5x
// headroom so free).  n varies fastest within an XCD chunk -> the m-row
// A-panel (1 MB) stays hot in that XCD's L2.
__global__ __launch_bounds__(256) void k_gemm(const unsigned short* __restrict__ hbuf,
                                              const unsigned short* __restrict__ w2b,
                                              const int* __restrict__ idx,
                                              const int* __restrict__ counters,
                                              const float* __restrict__ b2,
                                              const float* __restrict__ te2,
                                              float* __restrict__ out) {
    int count = counters[0], padded = counters[1];
    int flat = blockIdx.y * 32 + blockIdx.x;
    int active = (padded >> 7) * 32;          // multiple of 32 (and of 8)
    if (flat >= active) return;
    int q = active >> 3;
    int nid = (flat & 7) * q + (flat >> 3);   // bijective XCD-chunked swizzle
    int m0 = (nid >> 5) * 128;                // n varies fastest within chunk
    int n0 = (nid & 31) * 128;

    __shared__ unsigned short At[128 * 32];
    __shared__ unsigned short Bt[128 * 32];

    int t = threadIdx.x;
    int lane = t & 63, wave = t >> 6;
    int wm = (wave >> 1) * 64;
    int wn = (wave & 1) * 64;

    int srow = t >> 2, skg = t & 3;
    const unsigned short* Ag = hbuf + (size_t)(m0 + srow) * EMBED + skg * 8;
    const unsigned short* Bg = w2b + (size_t)(n0 + srow) * EMBED + skg * 8;
    char* AtC = (char*)At;
    char* BtC = (char*)Bt;
    int ldsw = (t & ~63) * 16;

    f4_t acc[4][4];
#pragma unroll
    for (int i = 0; i < 4; ++i)
#pragma unroll
        for (int j = 0; j < 4; ++j) acc[i][j] = (f4_t)0.f;

    int fr = lane & 15;
    int quad = lane >> 4;

    for (int k0 = 0; k0 < EMBED; k0 += 32) {
        __syncthreads();
        gl_lds16(Ag + k0,               AtC + ldsw);
        gl_lds16(Ag + 64 * EMBED + k0,  AtC + 4096 + ldsw);
        gl_lds16(Bg + k0,               BtC + ldsw);
        gl_lds16(Bg + 64 * EMBED + k0,  BtC + 4096 + ldsw);
        __syncthreads();

        bf16x8 a[4], b[4];
#pragma unroll
        for (int i = 0; i < 4; ++i) {
            a[i] = *(const bf16x8*)(AtC + (wm + i * 16 + fr) * 64 + quad * 16);
            b[i] = *(const bf16x8*)(BtC + (wn + i * 16 + fr) * 64 + quad * 16);
        }
#pragma unroll
        for (int i = 0; i < 4; ++i)
#pragma unroll
            for (int j = 0; j < 4; ++j)
                acc[i][j] = __builtin_amdgcn_mfma_f32_16x16x32_bf16(a[i], b[j], acc[i][j], 0, 0, 0);
    }

#pragma unroll
    for (int i = 0; i < 4; ++i) {
#pragma unroll
        for (int r = 0; r < 4; ++r) {
            int grow = m0 + wm + i * 16 + quad * 4 + r;
            if (grow < count) {
                float* orow = out + (size_t)idx[grow] * EMBED;
#pragma unroll
                for (int j = 0; j < 4; ++j) {
                    int gcol = n0 + wn + j * 16 + fr;
                    orow[gcol] = acc[i][j][r] + b2[gcol] + te2[gcol];
                }
            }
        }
    }
}

extern "C" void kernel_launch(void* const* d_in, const int* in_sizes, int n_in,
                              void* d_out, int out_size, void* d_ws, size_t ws_size,
                              hipStream_t stream) {
    const float* prompts  = (const float*)d_in[0];
    const int*   types    = (const int*)d_in[1];
    const float* point_w  = (const float*)d_in[2];
    const float* point_b  = (const float*)d_in[3];
    const float* box_w    = (const float*)d_in[4];
    const float* box_b    = (const float*)d_in[5];
    const float* poly_w1  = (const float*)d_in[6];
    const float* poly_b1  = (const float*)d_in[7];
    const float* ln_g     = (const float*)d_in[8];
    const float* ln_b     = (const float*)d_in[9];
    const float* poly_w2  = (const float*)d_in[10];
    const float* poly_b2  = (const float*)d_in[11];
    const float* type_emb = (const float*)d_in[12];
    float* out = (float*)d_out;

    char* ws = (char*)d_ws;
    int*   counters = (int*)ws;                               // 2 ints
    int*   idx      = (int*)(ws + 256);                       // 8192 ints
    float* cbar     = (float*)(ws + 33280);                   // 65 f
    float* G        = (float*)(ws + 33792);                   // 65*65 f
    float* muarr    = (float*)(ws + 51200);                   // 8192 f
    float* rstdarr  = (float*)(ws + 84224);                   // 8192 f
    unsigned short* xbuf = (unsigned short*)(ws + 131072);    // 1 MB
    unsigned short* w1b  = (unsigned short*)(ws + 131072 + 1048576);  // 512 KB
    unsigned short* w2b  = (unsigned short*)(ws + 2097152);   // 32 MB
    unsigned short* hbuf = (unsigned short*)(ws + 2097152 + (size_t)EMBED * EMBED * 2); // 64 MB

    int nprep = 67 + NB_CONVW2 + NB_CONVW1 + NTOK;
    k_prep<<<nprep, 256, 0, stream>>>(prompts, types, point_w, point_b,
                                      box_w, box_b, type_emb,
                                      poly_w1, poly_b1, poly_w2,
                                      idx, counters, G, cbar, w1b, w2b, out);
    k_stats<<<NTOK / 4, 256, 0, stream>>>(prompts, idx, counters, cbar, G,
                                          muarr, rstdarr, xbuf);
    k_lin1m<<<dim3(EMBED / 128, NTOK / 128), 256, 0, stream>>>(
        xbuf, w1b, counters, poly_b1, ln_g, ln_b, muarr, rstdarr, hbuf);
    k_gemm<<<dim3(EMBED / 128, NTOK / 128), 256, 0, stream>>>(
        hbuf, w2b, idx, counters, poly_b2, type_emb + 2 * EMBED, out);
}